// Round 5
// baseline (48.581 us; speedup 1.0000x reference)
//
#include <hip/hip_runtime.h>
#include <math.h>

#define BATCH 8
#define NPTS 4096
#define BN (BATCH * NPTS)     /* 32768 */
#define G 8                   /* cell grid G x G          */
#define NCELL (G * G)         /* 64 cells                 */
#define WPB 8                 /* waves per main block     */
#define TPBM (WPB * 64)       /* 512 threads              */
#define IBLK 64               /* i-points per main block  */
#define ESHIFT 96.0f
#define LOG2E 1.4426950408889634f
#define INV_PI 0.3183098861837907f

typedef float v2f __attribute__((ext_vector_type(2)));

static __device__ __forceinline__ float fast_exp2(float x) {
#if __has_builtin(__builtin_amdgcn_exp2f)
    return __builtin_amdgcn_exp2f(x);
#else
    return exp2f(x);
#endif
}

// ---------------- deterministic counting sort (one block per batch) ---------
// Stable order: group-major (4 groups of 1024) -> wave-major -> lane order.
__global__ __launch_bounds__(1024)
void kde_sort(const float* __restrict__ w, const float* __restrict__ c,
              const float* __restrict__ sigma,
              float* __restrict__ sjx, float* __restrict__ sjy,
              float* __restrict__ sjc, float* __restrict__ six,
              float* __restrict__ siy, int* __restrict__ sidx,
              int* __restrict__ cellStartG) {
    __shared__ int cid[NPTS];        // 16 KB
    __shared__ int wh[16][NCELL];    // per-wave histogram of current group
    __shared__ int hist[NCELL];
    __shared__ int runBase[NCELL];

    int b = blockIdx.x;
    int t = threadIdx.x;
    const float2* cb = (const float2*)c + b * NPTS;

    if (t < NCELL) hist[t] = 0;
    __syncthreads();

    for (int g = 0; g < 4; ++g) {
        int p = g * 1024 + t;
        float2 cc = cb[p];
        int cx = min(G - 1, max(0, (int)(cc.x * (float)G)));
        int cy = min(G - 1, max(0, (int)(cc.y * (float)G)));
        int cell = cy * G + cx;
        cid[p] = cell;
        atomicAdd(&hist[cell], 1);   // LDS atomic: deterministic counts
    }
    __syncthreads();

    if (t < 64) {                    // wave 0: exclusive scan over 64 cells
        int v = hist[t];
        int s = v;
        for (int d = 1; d < 64; d <<= 1) {
            int o = __shfl_up(s, d, 64);
            if (t >= d) s += o;
        }
        int excl = s - v;
        runBase[t] = excl;
        cellStartG[b * (NCELL + 1) + t] = excl;
        if (t == 63) cellStartG[b * (NCELL + 1) + NCELL] = s;  // = NPTS
    }
    __syncthreads();

    float sg  = sigma[0];
    float kap = LOG2E / (2.0f * sg * sg);

    for (int g = 0; g < 4; ++g) {
        int p    = g * 1024 + t;
        int lane = t & 63, wv = t >> 6;
        int mycell = cid[p];

        wh[wv][lane] = 0;            // 16x64 zeroed by 1024 threads
        __syncthreads();

        int base = g * 1024 + wv * 64;
        int rank = 0, cnt = 0;
        for (int q = 0; q < 64; ++q) {
            int eq = (cid[base + q] == mycell);
            cnt += eq;
            rank += (q < lane) ? eq : 0;
        }
        if (rank == 0) wh[wv][mycell] = cnt;   // unique writer per (wave,cell)
        __syncthreads();

        int wo = 0;
        for (int w2 = 0; w2 < wv; ++w2) wo += wh[w2][mycell];
        int pos = runBase[mycell] + wo + rank;

        // scatter transformed point data to sorted position
        float2 cc = cb[p];
        float xj = cc.x - 0.5f, yj = cc.y - 0.5f;
        float ww = w[b * NPTS + p];
        float aj = fmaf(xj, xj, yj * yj);
        int o = b * NPTS + pos;
        sjx[o] = 2.0f * kap * xj;
        sjy[o] = 2.0f * kap * yj;
        sjc[o] = fmaf(-kap, aj, log2f(ww) - ESHIFT);
        six[o] = xj;
        siy[o] = yj;
        sidx[o] = p;
        __syncthreads();

        if (t < NCELL) {             // advance running bases by group totals
            int r = runBase[t];
            for (int w2 = 0; w2 < 16; ++w2) r += wh[w2][t];
            runBase[t] = r;
        }
        __syncthreads();
    }
}

// ---------------- windowed main: block owns 64 sorted i-points --------------
__global__ __launch_bounds__(TPBM)
void kde_main(const float* __restrict__ sjx, const float* __restrict__ sjy,
              const float* __restrict__ sjc, const float* __restrict__ six,
              const float* __restrict__ siy, const int* __restrict__ sidx,
              const int* __restrict__ cellStartG,
              const float* __restrict__ sigma, float* __restrict__ out) {
    __shared__ __align__(16) float shx[WPB][64];
    __shared__ __align__(16) float shy[WPB][64];
    __shared__ __align__(16) float shc[WPB][64];
    __shared__ float shs[WPB][64];

    int b = blockIdx.y, blk = blockIdx.x;
    int t = threadIdx.x, lane = t & 63, wv = t >> 6;
    int spos = b * NPTS + blk * IBLK + lane;

    float xi = six[spos], yi = siy[spos];
    int oidx = sidx[spos];

    float sg   = sigma[0];
    float kape = 1.0f / (2.0f * sg * sg);
    float R    = sqrtf(13.0f / kape);   // dropped-tail bound: N*e^-13*norm ~ 0.6 << 55

    // exact bbox of this block's 64 i-points (identical in every wave)
    float xmn = xi, xmx = xi, ymn = yi, ymx = yi;
    for (int d = 1; d < 64; d <<= 1) {
        xmn = fminf(xmn, __shfl_xor(xmn, d, 64));
        xmx = fmaxf(xmx, __shfl_xor(xmx, d, 64));
        ymn = fminf(ymn, __shfl_xor(ymn, d, 64));
        ymx = fmaxf(ymx, __shfl_xor(ymx, d, 64));
    }
    int rLo = max(0,     (int)floorf((ymn + 0.5f - R) * (float)G));
    int rHi = min(G - 1, (int)floorf((ymx + 0.5f + R) * (float)G));
    int cLo = max(0,     (int)floorf((xmn + 0.5f - R) * (float)G));
    int cHi = min(G - 1, (int)floorf((xmx + 0.5f + R) * (float)G));

    v2f xi2 = {xi, xi}, yi2 = {yi, yi}, acc = {0.0f, 0.0f};
    const int cb0 = b * (NCELL + 1);
    const int jbase = b * NPTS;

    for (int row = rLo; row <= rHi; ++row) {
        int s = cellStartG[cb0 + row * G + cLo];
        int e = cellStartG[cb0 + row * G + cHi + 1];
        for (int t0 = s + 64 * wv; t0 < e; t0 += 64 * WPB) {
            int jt = t0 + lane;
            bool val = jt < e;
            int ja = jbase + jt;
            shx[wv][lane] = val ? sjx[ja] : 0.0f;
            shy[wv][lane] = val ? sjy[ja] : 0.0f;
            shc[wv][lane] = val ? sjc[ja] : -1e30f;   // sentinel -> exp2 -> 0
            asm volatile("s_waitcnt lgkmcnt(0)" ::: "memory");
#pragma unroll
            for (int k = 0; k < 64; k += 4) {
                float4 X = *(const float4*)&shx[wv][k];  // ds_read_b128 bcast
                float4 Y = *(const float4*)&shy[wv][k];
                float4 C = *(const float4*)&shc[wv][k];
                v2f xa = {X.x, X.y}, xb = {X.z, X.w};
                v2f ya = {Y.x, Y.y}, yb = {Y.z, Y.w};
                v2f ca = {C.x, C.y}, cb2 = {C.z, C.w};
                v2f ta = yi2 * ya + ca;
                v2f aa = xi2 * xa + ta;
                v2f tb = yi2 * yb + cb2;
                v2f ab = xi2 * xb + tb;
                acc += (v2f){fast_exp2(aa.x), fast_exp2(aa.y)};
                acc += (v2f){fast_exp2(ab.x), fast_exp2(ab.y)};
            }
            asm volatile("s_waitcnt lgkmcnt(0)" ::: "memory");
        }
    }

    shs[wv][lane] = acc.x + acc.y;
    __syncthreads();
    if (wv == 0) {
        float s = 0.0f;
#pragma unroll
        for (int w2 = 0; w2 < WPB; ++w2) s += shs[w2][lane];
        float kapl = LOG2E * kape;
        float norm = kape * INV_PI;           // 1/(2*pi*sg^2)
        float ai = fmaf(xi, xi, yi * yi);
        float fi = norm * exp2f(fmaf(-kapl, ai, ESHIFT));
        out[b * NPTS + oidx] = fi * s;
    }
}

extern "C" void kernel_launch(void* const* d_in, const int* in_sizes, int n_in,
                              void* d_out, int out_size, void* d_ws, size_t ws_size,
                              hipStream_t stream) {
    const float* w     = (const float*)d_in[0];
    const float* c     = (const float*)d_in[1];
    const float* sigma = (const float*)d_in[2];
    float* out = (float*)d_out;

    float* ws  = (float*)d_ws;
    float* sjx = ws;
    float* sjy = ws + (size_t)BN;
    float* sjc = ws + (size_t)2 * BN;
    float* six = ws + (size_t)3 * BN;
    float* siy = ws + (size_t)4 * BN;
    int*   sidx = (int*)(ws + (size_t)5 * BN);
    int*   cst  = sidx + BN;                  // [BATCH][NCELL+1]

    kde_sort<<<BATCH, 1024, 0, stream>>>(w, c, sigma,
                                         sjx, sjy, sjc, six, siy, sidx, cst);
    kde_main<<<dim3(NPTS / IBLK, BATCH), TPBM, 0, stream>>>(
        sjx, sjy, sjc, six, siy, sidx, cst, sigma, out);
}

// Round 6
// 41.000 us; speedup vs baseline: 1.1849x; 1.1849x over previous
//
#include <hip/hip_runtime.h>
#include <math.h>

#define BATCH 8
#define NPTS 4096
#define BN (BATCH * NPTS)     /* 32768 */
#define G 8                   /* cell grid G x G            */
#define NCELL (G * G)         /* 64 cells                   */
#define NBLK 16               /* sort blocks per batch      */
#define SPTS 256              /* points per sort block      */
#define WPB 8                 /* waves per main block       */
#define TPBM (WPB * 64)       /* 512 threads                */
#define IBLK 64               /* i-points per main block    */
#define ESHIFT 96.0f
#define LOG2E 1.4426950408889634f
#define INV_PI 0.3183098861837907f

typedef float v2f __attribute__((ext_vector_type(2)));

static __device__ __forceinline__ float fast_exp2(float x) {
#if __has_builtin(__builtin_amdgcn_exp2f)
    return __builtin_amdgcn_exp2f(x);
#else
    return exp2f(x);
#endif
}

// ---- Stage A: cell ids + per-block histograms (128 blocks) -----------------
__global__ __launch_bounds__(SPTS)
void kde_cells(const float* __restrict__ c, int* __restrict__ cid,
               int* __restrict__ histB) {
    int b = blockIdx.y, blk = blockIdx.x, t = threadIdx.x;
    int p = blk * SPTS + t;
    __shared__ int h[NCELL];
    if (t < NCELL) h[t] = 0;
    __syncthreads();
    float2 cc = ((const float2*)c)[b * NPTS + p];
    int cx = min(G - 1, max(0, (int)(cc.x * (float)G)));
    int cy = min(G - 1, max(0, (int)(cc.y * (float)G)));
    int cell = cy * G + cx;
    cid[b * NPTS + p] = cell;
    atomicAdd(&h[cell], 1);
    __syncthreads();
    if (t < NCELL) histB[(b * NBLK + blk) * NCELL + t] = h[t];
}

// ---- Stage B: per-batch scan (8 blocks x 1 wave) ---------------------------
__global__ __launch_bounds__(64)
void kde_scan(const int* __restrict__ histB, int* __restrict__ blockOff,
              int* __restrict__ cst) {
    int b = blockIdx.x, cell = threadIdx.x;      // 64 threads = 64 cells
    int pre[NBLK];
    int s = 0;
#pragma unroll
    for (int blk = 0; blk < NBLK; ++blk) {
        pre[blk] = s;
        s += histB[(b * NBLK + blk) * NCELL + cell];
    }
    int run = s;                                  // exclusive scan over cells
    for (int d = 1; d < 64; d <<= 1) {
        int o = __shfl_up(run, d, 64);
        if (cell >= d) run += o;
    }
    int excl = run - s;
    cst[b * (NCELL + 1) + cell] = excl;
    if (cell == 63) cst[b * (NCELL + 1) + NCELL] = excl + s;   // = NPTS
#pragma unroll
    for (int blk = 0; blk < NBLK; ++blk)
        blockOff[(b * NBLK + blk) * NCELL + cell] = excl + pre[blk];
}

// ---- Stage C: stable scatter of transformed point data (128 blocks) --------
__global__ __launch_bounds__(SPTS)
void kde_scatter(const float* __restrict__ w, const float* __restrict__ c,
                 const float* __restrict__ sigma,
                 const int* __restrict__ cid, const int* __restrict__ blockOff,
                 float* __restrict__ sjx, float* __restrict__ sjy,
                 float* __restrict__ sjc, float* __restrict__ six,
                 float* __restrict__ siy, int* __restrict__ sidx) {
    int b = blockIdx.y, blk = blockIdx.x, t = threadIdx.x;
    int p = blk * SPTS + t;
    __shared__ int cs[SPTS];
    int cell = cid[b * NPTS + p];
    cs[t] = cell;
    __syncthreads();
    int rank = 0;
    for (int q = 0; q < SPTS; ++q)               // stable in-block rank
        rank += (q < t && cs[q] == cell);
    int pos = blockOff[(b * NBLK + blk) * NCELL + cell] + rank;

    float sg  = sigma[0];
    float kap = LOG2E / (2.0f * sg * sg);
    float2 cc = ((const float2*)c)[b * NPTS + p];
    float xj = cc.x - 0.5f, yj = cc.y - 0.5f;
    float ww = w[b * NPTS + p];
    float aj = fmaf(xj, xj, yj * yj);
    int o = b * NPTS + pos;
    sjx[o] = 2.0f * kap * xj;
    sjy[o] = 2.0f * kap * yj;
    sjc[o] = fmaf(-kap, aj, log2f(ww) - ESHIFT);
    six[o] = xj;
    siy[o] = yj;
    sidx[o] = p;
}

// ---- Stage D: windowed main (512 blocks x 8 waves) -------------------------
__global__ __launch_bounds__(TPBM)
void kde_main(const float* __restrict__ sjx, const float* __restrict__ sjy,
              const float* __restrict__ sjc, const float* __restrict__ six,
              const float* __restrict__ siy, const int* __restrict__ sidx,
              const int* __restrict__ cst,
              const float* __restrict__ sigma, float* __restrict__ out) {
    __shared__ __align__(16) float shx[WPB][64];
    __shared__ __align__(16) float shy[WPB][64];
    __shared__ __align__(16) float shc[WPB][64];
    __shared__ float shs[WPB][64];

    int b = blockIdx.y, blk = blockIdx.x;
    int t = threadIdx.x, lane = t & 63, wv = t >> 6;
    int spos = b * NPTS + blk * IBLK + lane;

    float xi = six[spos], yi = siy[spos];
    int oidx = sidx[spos];

    float sg   = sigma[0];
    float kape = 1.0f / (2.0f * sg * sg);
    float R    = sqrtf(13.0f / kape);   // tail bound: N*e^-13*norm ~ 0.6 << 55

    float xmn = xi, xmx = xi, ymn = yi, ymx = yi;
    for (int d = 1; d < 64; d <<= 1) {
        xmn = fminf(xmn, __shfl_xor(xmn, d, 64));
        xmx = fmaxf(xmx, __shfl_xor(xmx, d, 64));
        ymn = fminf(ymn, __shfl_xor(ymn, d, 64));
        ymx = fmaxf(ymx, __shfl_xor(ymx, d, 64));
    }
    int rLo = max(0,     (int)floorf((ymn + 0.5f - R) * (float)G));
    int rHi = min(G - 1, (int)floorf((ymx + 0.5f + R) * (float)G));
    int cLo = max(0,     (int)floorf((xmn + 0.5f - R) * (float)G));
    int cHi = min(G - 1, (int)floorf((xmx + 0.5f + R) * (float)G));

    v2f xi2 = {xi, xi}, yi2 = {yi, yi}, acc = {0.0f, 0.0f};
    const int cb0 = b * (NCELL + 1);
    const int jbase = b * NPTS;

    for (int row = rLo; row <= rHi; ++row) {
        int s = cst[cb0 + row * G + cLo];
        int e = cst[cb0 + row * G + cHi + 1];
        for (int t0 = s + 64 * wv; t0 < e; t0 += 64 * WPB) {
            int jt = t0 + lane;
            bool val = jt < e;
            int ja = jbase + jt;
            shx[wv][lane] = val ? sjx[ja] : 0.0f;
            shy[wv][lane] = val ? sjy[ja] : 0.0f;
            shc[wv][lane] = val ? sjc[ja] : -1e30f;   // sentinel -> exp2 -> 0
            asm volatile("s_waitcnt lgkmcnt(0)" ::: "memory");
#pragma unroll
            for (int k = 0; k < 64; k += 4) {
                float4 X = *(const float4*)&shx[wv][k];  // ds_read_b128 bcast
                float4 Y = *(const float4*)&shy[wv][k];
                float4 C = *(const float4*)&shc[wv][k];
                v2f xa = {X.x, X.y}, xb = {X.z, X.w};
                v2f ya = {Y.x, Y.y}, yb = {Y.z, Y.w};
                v2f ca = {C.x, C.y}, cb2 = {C.z, C.w};
                v2f ta = yi2 * ya + ca;
                v2f aa = xi2 * xa + ta;
                v2f tb = yi2 * yb + cb2;
                v2f ab = xi2 * xb + tb;
                acc += (v2f){fast_exp2(aa.x), fast_exp2(aa.y)};
                acc += (v2f){fast_exp2(ab.x), fast_exp2(ab.y)};
            }
            asm volatile("s_waitcnt lgkmcnt(0)" ::: "memory");
        }
    }

    shs[wv][lane] = acc.x + acc.y;
    __syncthreads();
    if (wv == 0) {
        float s = 0.0f;
#pragma unroll
        for (int w2 = 0; w2 < WPB; ++w2) s += shs[w2][lane];
        float kapl = LOG2E * kape;
        float norm = kape * INV_PI;              // 1/(2*pi*sg^2)
        float ai = fmaf(xi, xi, yi * yi);
        float fi = norm * exp2f(fmaf(-kapl, ai, ESHIFT));
        out[b * NPTS + oidx] = fi * s;
    }
}

extern "C" void kernel_launch(void* const* d_in, const int* in_sizes, int n_in,
                              void* d_out, int out_size, void* d_ws, size_t ws_size,
                              hipStream_t stream) {
    const float* w     = (const float*)d_in[0];
    const float* c     = (const float*)d_in[1];
    const float* sigma = (const float*)d_in[2];
    float* out = (float*)d_out;

    float* ws  = (float*)d_ws;
    float* sjx = ws;
    float* sjy = ws + (size_t)BN;
    float* sjc = ws + (size_t)2 * BN;
    float* six = ws + (size_t)3 * BN;
    float* siy = ws + (size_t)4 * BN;
    int*   sidx    = (int*)(ws + (size_t)5 * BN);
    int*   cid     = sidx + BN;
    int*   histB   = cid + BN;                    // [8][16][64]
    int*   blockOff= histB + BATCH * NBLK * NCELL;
    int*   cst     = blockOff + BATCH * NBLK * NCELL;  // [8][65]

    kde_cells<<<dim3(NBLK, BATCH), SPTS, 0, stream>>>(c, cid, histB);
    kde_scan<<<BATCH, 64, 0, stream>>>(histB, blockOff, cst);
    kde_scatter<<<dim3(NBLK, BATCH), SPTS, 0, stream>>>(
        w, c, sigma, cid, blockOff, sjx, sjy, sjc, six, siy, sidx);
    kde_main<<<dim3(NPTS / IBLK, BATCH), TPBM, 0, stream>>>(
        sjx, sjy, sjc, six, siy, sidx, cst, sigma, out);
}

// Round 7
// 37.756 us; speedup vs baseline: 1.2867x; 1.0859x over previous
//
#include <hip/hip_runtime.h>
#include <math.h>

#define BATCH 8
#define NPTS 4096
#define BN (BATCH * NPTS)     /* 32768 */
#define G 8                   /* cell grid G x G            */
#define NCELL (G * G)         /* 64 cells                   */
#define NBLK 16               /* sort blocks per batch      */
#define SPTS 256              /* points per sort block      */
#define WPB 8                 /* waves per main block       */
#define TPBM (WPB * 64)       /* 512 threads                */
#define IBLK 128              /* i-points per main block (RBLK=2) */
#define NMB (NPTS / IBLK)     /* 32 main blocks per batch   */
#define ESHIFT 96.0f
#define LOG2E 1.4426950408889634f
#define INV_PI 0.3183098861837907f

typedef float v2f __attribute__((ext_vector_type(2)));

static __device__ __forceinline__ float fast_exp2(float x) {
#if __has_builtin(__builtin_amdgcn_exp2f)
    return __builtin_amdgcn_exp2f(x);
#else
    return exp2f(x);
#endif
}

static __device__ __forceinline__ int cell_of(float2 cc) {
    int cx = min(G - 1, max(0, (int)(cc.x * (float)G)));
    int cy = min(G - 1, max(0, (int)(cc.y * (float)G)));
    return cy * G + cx;
}

// ---- Stage A: per-block cell histograms (128 blocks) -----------------------
__global__ __launch_bounds__(SPTS)
void kde_cells(const float* __restrict__ c, int* __restrict__ histB) {
    int b = blockIdx.y, blk = blockIdx.x, t = threadIdx.x;
    __shared__ int h[NCELL];
    if (t < NCELL) h[t] = 0;
    __syncthreads();
    float2 cc = ((const float2*)c)[b * NPTS + blk * SPTS + t];
    atomicAdd(&h[cell_of(cc)], 1);
    __syncthreads();
    if (t < NCELL) histB[(b * NBLK + blk) * NCELL + t] = h[t];
}

// ---- Stage B: scan (redundant per block) + stable scatter (128 blocks) -----
__global__ __launch_bounds__(SPTS)
void kde_scatter(const float* __restrict__ w, const float* __restrict__ c,
                 const float* __restrict__ sigma, const int* __restrict__ histB,
                 float* __restrict__ sjx, float* __restrict__ sjy,
                 float* __restrict__ sjc, float* __restrict__ six,
                 float* __restrict__ siy, int* __restrict__ sidx,
                 int* __restrict__ cst) {
    int b = blockIdx.y, blk = blockIdx.x, t = threadIdx.x;
    __shared__ int boff[NCELL];
    __shared__ int cs[SPTS];

    if (t < NCELL) {                      // wave 0 only: per-cell offsets
        int tot = 0, pre = 0;
#pragma unroll
        for (int k = 0; k < NBLK; ++k) {
            int v = histB[(b * NBLK + k) * NCELL + t];
            pre += (k < blk) ? v : 0;
            tot += v;
        }
        int run = tot;                    // exclusive scan over 64 cells
        for (int d = 1; d < 64; d <<= 1) {
            int o = __shfl_up(run, d, 64);
            if (t >= d) run += o;
        }
        int excl = run - tot;
        boff[t] = excl + pre;
        if (blk == 0) {
            cst[b * (NCELL + 1) + t] = excl;
            if (t == 63) cst[b * (NCELL + 1) + NCELL] = excl + tot;  // = NPTS
        }
    }
    int p = blk * SPTS + t;
    float2 cc = ((const float2*)c)[b * NPTS + p];
    int cell = cell_of(cc);
    cs[t] = cell;
    __syncthreads();

    int rank = 0;
    for (int q = 0; q < SPTS; ++q)        // stable in-block rank
        rank += (q < t && cs[q] == cell);
    int pos = boff[cell] + rank;

    float sg  = sigma[0];
    float kap = LOG2E / (2.0f * sg * sg);
    float xj = cc.x - 0.5f, yj = cc.y - 0.5f;
    float aj = fmaf(xj, xj, yj * yj);
    int o = b * NPTS + pos;
    sjx[o] = 2.0f * kap * xj;
    sjy[o] = 2.0f * kap * yj;
    sjc[o] = fmaf(-kap, aj, log2f(w[b * NPTS + p]) - ESHIFT);
    six[o] = xj;
    siy[o] = yj;
    sidx[o] = p;
}

// ---- Stage C: windowed main, flattened j-iteration, RBLK=2 -----------------
__global__ __launch_bounds__(TPBM)
void kde_main(const float* __restrict__ sjx, const float* __restrict__ sjy,
              const float* __restrict__ sjc, const float* __restrict__ six,
              const float* __restrict__ siy, const int* __restrict__ sidx,
              const int* __restrict__ cst,
              const float* __restrict__ sigma, float* __restrict__ out) {
    __shared__ __align__(16) float shx[WPB][64];
    __shared__ __align__(16) float shy[WPB][64];
    __shared__ __align__(16) float shc[WPB][64];
    __shared__ float shs[WPB][2][64];

    int b = blockIdx.y, blk = blockIdx.x;
    int t = threadIdx.x, lane = t & 63, wv = t >> 6;
    int base = b * NPTS + blk * IBLK;

    float xi0 = six[base + lane],      yi0 = siy[base + lane];
    float xi1 = six[base + 64 + lane], yi1 = siy[base + 64 + lane];

    float sg   = sigma[0];
    float kape = 1.0f / (2.0f * sg * sg);
    float R    = sqrtf(13.0f / kape);   // tail bound: N*e^-13*norm ~ 0.6 << 55

    // bbox over the block's 128 i-points (identical in every wave)
    float xmn = fminf(xi0, xi1), xmx = fmaxf(xi0, xi1);
    float ymn = fminf(yi0, yi1), ymx = fmaxf(yi0, yi1);
    for (int d = 1; d < 64; d <<= 1) {
        xmn = fminf(xmn, __shfl_xor(xmn, d, 64));
        xmx = fmaxf(xmx, __shfl_xor(xmx, d, 64));
        ymn = fminf(ymn, __shfl_xor(ymn, d, 64));
        ymx = fmaxf(ymx, __shfl_xor(ymx, d, 64));
    }
    int rLo = max(0,     (int)floorf((ymn + 0.5f - R) * (float)G));
    int rHi = min(G - 1, (int)floorf((ymx + 0.5f + R) * (float)G));
    int cLo = max(0,     (int)floorf((xmn + 0.5f - R) * (float)G));
    int cHi = min(G - 1, (int)floorf((xmx + 0.5f + R) * (float)G));

    // flattened window: prefix P[k], delta D[k] (full unroll -> static idx)
    const int* cb = cst + b * (NCELL + 1);
    int P[8], D[8];
    int accP = 0;
    #pragma unroll
    for (int k = 0; k < 8; ++k) {
        int row = rLo + k;
        int s_ = 0, e_ = 0;
        if (row <= rHi) { s_ = cb[row * G + cLo]; e_ = cb[row * G + cHi + 1]; }
        P[k] = accP;
        D[k] = s_ - accP;
        accP += (e_ - s_);
    }
    int L = accP;
    int NT = (L + 63) >> 6;
    const int jbase = b * NPTS;

    v2f xa0 = {xi0, xi0}, ya0 = {yi0, yi0};
    v2f xa1 = {xi1, xi1}, ya1 = {yi1, yi1};
    v2f acc0 = {0.0f, 0.0f}, acc1 = {0.0f, 0.0f};

    for (int T = wv; T < NT; T += WPB) {
        int g = T * 64 + lane;
        int d = D[0];
        #pragma unroll
        for (int k = 1; k < 8; ++k) d = (g >= P[k]) ? D[k] : d;
        bool valid = g < L;
        int j  = valid ? (g + d) : 0;
        int ja = jbase + j;
        shx[wv][lane] = sjx[ja];
        shy[wv][lane] = sjy[ja];
        shc[wv][lane] = valid ? sjc[ja] : -1e30f;   // sentinel -> exp2 -> 0
        asm volatile("s_waitcnt lgkmcnt(0)" ::: "memory");
#pragma unroll
        for (int k = 0; k < 64; k += 4) {
            float4 X = *(const float4*)&shx[wv][k];  // ds_read_b128 bcast
            float4 Y = *(const float4*)&shy[wv][k];
            float4 C = *(const float4*)&shc[wv][k];
            v2f jx0 = {X.x, X.y}, jx1 = {X.z, X.w};
            v2f jy0 = {Y.x, Y.y}, jy1 = {Y.z, Y.w};
            v2f jc0 = {C.x, C.y}, jc1 = {C.z, C.w};
            v2f e00 = xa0 * jx0 + (ya0 * jy0 + jc0);
            v2f e01 = xa0 * jx1 + (ya0 * jy1 + jc1);
            v2f e10 = xa1 * jx0 + (ya1 * jy0 + jc0);
            v2f e11 = xa1 * jx1 + (ya1 * jy1 + jc1);
            acc0 += (v2f){fast_exp2(e00.x), fast_exp2(e00.y)};
            acc0 += (v2f){fast_exp2(e01.x), fast_exp2(e01.y)};
            acc1 += (v2f){fast_exp2(e10.x), fast_exp2(e10.y)};
            acc1 += (v2f){fast_exp2(e11.x), fast_exp2(e11.y)};
        }
        asm volatile("s_waitcnt lgkmcnt(0)" ::: "memory");
    }

    shs[wv][0][lane] = acc0.x + acc0.y;
    shs[wv][1][lane] = acc1.x + acc1.y;
    __syncthreads();
    if (wv < 2) {                         // wave wv finalizes i-set wv
        float s = 0.0f;
#pragma unroll
        for (int w2 = 0; w2 < WPB; ++w2) s += shs[w2][wv][lane];
        int sp = base + wv * 64 + lane;
        float xi = six[sp], yi = siy[sp];
        float kapl = LOG2E * kape;
        float norm = kape * INV_PI;       // 1/(2*pi*sg^2)
        float ai = fmaf(xi, xi, yi * yi);
        float fi = norm * fast_exp2(fmaf(-kapl, ai, ESHIFT));
        out[b * NPTS + sidx[sp]] = fi * s;
    }
}

extern "C" void kernel_launch(void* const* d_in, const int* in_sizes, int n_in,
                              void* d_out, int out_size, void* d_ws, size_t ws_size,
                              hipStream_t stream) {
    const float* w     = (const float*)d_in[0];
    const float* c     = (const float*)d_in[1];
    const float* sigma = (const float*)d_in[2];
    float* out = (float*)d_out;

    float* ws  = (float*)d_ws;
    float* sjx = ws;
    float* sjy = ws + (size_t)BN;
    float* sjc = ws + (size_t)2 * BN;
    float* six = ws + (size_t)3 * BN;
    float* siy = ws + (size_t)4 * BN;
    int*   sidx  = (int*)(ws + (size_t)5 * BN);
    int*   histB = sidx + BN;                      // [8][16][64]
    int*   cst   = histB + BATCH * NBLK * NCELL;   // [8][65]

    kde_cells<<<dim3(NBLK, BATCH), SPTS, 0, stream>>>(c, histB);
    kde_scatter<<<dim3(NBLK, BATCH), SPTS, 0, stream>>>(
        w, c, sigma, histB, sjx, sjy, sjc, six, siy, sidx, cst);
    kde_main<<<dim3(NMB, BATCH), TPBM, 0, stream>>>(
        sjx, sjy, sjc, six, siy, sidx, cst, sigma, out);
}

// Round 8
// 25.308 us; speedup vs baseline: 1.9196x; 1.4919x over previous
//
#include <hip/hip_runtime.h>
#include <math.h>

#define BATCH 8
#define NPTS 4096
#define BN (BATCH * NPTS)     /* 32768 */
#define NG 152                /* grid pitch; cells 0..150 used      */
#define NG2 (NG * NG)
#define X0 0.25f              /* grid origin at -0.25               */
#define INVH 100.0f           /* h = 0.01                           */
#define H 0.01f
#define KHW 23                /* tap half-width: 23h = 4.6 sigma    */
#define TAPS 47
#define FXS 262144.0f         /* 2^18 fixed-point splat scale       */
#define LOG2E 1.4426950408889634f
#define INV_TWO_PI 0.15915494309189535f

typedef unsigned int u32;

static __device__ __forceinline__ float fast_exp2(float x) {
#if __has_builtin(__builtin_amdgcn_exp2f)
    return __builtin_amdgcn_exp2f(x);
#else
    return exp2f(x);
#endif
}

// Gaussian taps with variance compensation: sg_g^2 = sg^2 - h^2/3 cancels
// the two bilinear hats (splat + interp), each adding h^2/6 variance/dim.
static __device__ __forceinline__ void load_taps(float* gt, const float* sigma, int t) {
    if (t < TAPS) {
        float sg   = sigma[0];
        float sg2g = fmaxf(sg * sg - (H * H) * (1.0f / 3.0f), 0.25f * sg * sg);
        float kap  = 1.0f / (2.0f * sg2g);
        float kk   = (float)(t - KHW) * H;
        gt[t] = fast_exp2(-kk * kk * kap * LOG2E);
    }
}

// ---- 1: bilinear splat, 2^18 fixed-point integer atomics (deterministic) ---
__global__ __launch_bounds__(256)
void kde_splat(const float* __restrict__ w, const float* __restrict__ c,
               u32* __restrict__ rho) {
    int idx = blockIdx.x * 256 + threadIdx.x;
    int b = idx >> 12;
    float2 cc = ((const float2*)c)[idx];
    float u = (cc.x + X0) * INVH;       // in [25,125)
    float v = (cc.y + X0) * INVH;
    int iu = (int)floorf(u), iv = (int)floorf(v);
    float fu = u - (float)iu, fv = v - (float)iv;
    float w18 = w[idx] * FXS;
    u32* g = rho + b * NG2 + iv * NG + iu;
    atomicAdd(&g[0],      (u32)(w18 * (1.0f - fu) * (1.0f - fv) + 0.5f));
    atomicAdd(&g[1],      (u32)(w18 * fu * (1.0f - fv) + 0.5f));
    atomicAdd(&g[NG],     (u32)(w18 * (1.0f - fu) * fv + 0.5f));
    atomicAdd(&g[NG + 1], (u32)(w18 * fu * fv + 0.5f));
}

// ---- 2: horizontal convolution: rows [2,149], cols [25,126] ----------------
__global__ __launch_bounds__(128)
void kde_convx(const u32* __restrict__ rho, const float* __restrict__ sigma,
               float* __restrict__ tmp) {
    __shared__ float gt[TAPS];
    int b = blockIdx.y, r = 2 + blockIdx.x, t = threadIdx.x;
    load_taps(gt, sigma, t);
    __syncthreads();
    if (t >= 102) return;
    int cc = 25 + t;
    const u32* row = rho + b * NG2 + r * NG + (cc - KHW);   // cols [2,149]
    float s = 0.0f;
#pragma unroll
    for (int k = 0; k < TAPS; ++k)
        s = fmaf(gt[k], (float)row[k], s);
    tmp[b * NG2 + r * NG + cc] = s;
}

// ---- 3: vertical convolution: rows [25,126], cols [25,126] -----------------
__global__ __launch_bounds__(128)
void kde_convy(const float* __restrict__ tmp, const float* __restrict__ sigma,
               float* __restrict__ sm) {
    __shared__ float gt[TAPS];
    int b = blockIdx.y, r = 25 + blockIdx.x, t = threadIdx.x;
    load_taps(gt, sigma, t);
    __syncthreads();
    if (t >= 102) return;
    int cc = 25 + t;
    const float* col = tmp + b * NG2 + (r - KHW) * NG + cc; // rows [2,149]
    float s = 0.0f;
#pragma unroll
    for (int k = 0; k < TAPS; ++k)
        s = fmaf(gt[k], col[k * NG], s);
    sm[b * NG2 + r * NG + cc] = s;
}

// ---- 4: bilinear eval at query points --------------------------------------
__global__ __launch_bounds__(256)
void kde_eval(const float* __restrict__ sm, const float* __restrict__ c,
              const float* __restrict__ sigma, float* __restrict__ out) {
    int idx = blockIdx.x * 256 + threadIdx.x;
    int b = idx >> 12;
    float2 cc = ((const float2*)c)[idx];
    float u = (cc.x + X0) * INVH;
    float v = (cc.y + X0) * INVH;
    int iu = (int)floorf(u), iv = (int)floorf(v);
    float fu = u - (float)iu, fv = v - (float)iv;
    const float* g = sm + b * NG2 + iv * NG + iu;
    float s00 = g[0], s10 = g[1], s01 = g[NG], s11 = g[NG + 1];
    float s0 = s00 + fu * (s10 - s00);
    float s1 = s01 + fu * (s11 - s01);
    float s  = s0 + fv * (s1 - s0);
    float sg = sigma[0];
    out[idx] = s * (INV_TWO_PI / (sg * sg)) * (1.0f / FXS);
}

extern "C" void kernel_launch(void* const* d_in, const int* in_sizes, int n_in,
                              void* d_out, int out_size, void* d_ws, size_t ws_size,
                              hipStream_t stream) {
    const float* w     = (const float*)d_in[0];
    const float* c     = (const float*)d_in[1];
    const float* sigma = (const float*)d_in[2];
    float* out = (float*)d_out;

    u32*   rho = (u32*)d_ws;                       // [8][152][152] fixed-point
    float* tmp = (float*)d_ws + (size_t)BATCH * NG2;
    float* sm  = tmp + (size_t)BATCH * NG2;

    hipMemsetAsync(rho, 0, (size_t)BATCH * NG2 * sizeof(u32), stream);
    kde_splat<<<BN / 256, 256, 0, stream>>>(w, c, rho);
    kde_convx<<<dim3(148, BATCH), 128, 0, stream>>>(rho, sigma, tmp);
    kde_convy<<<dim3(102, BATCH), 128, 0, stream>>>(tmp, sigma, sm);
    kde_eval<<<BN / 256, 256, 0, stream>>>(sm, c, sigma, out);
}

// Round 9
// 12.407 us; speedup vs baseline: 3.9156x; 2.0398x over previous
//
#include <hip/hip_runtime.h>
#include <math.h>

#define BATCH 8
#define NPTS 4096
#define TPB 1024
#define NG 80
#define NG2 (NG * NG)
#define ORGX 0.26f            /* grid origin at -0.26; u=(x+0.26)*50 in [13,63) */
#define INVH 50.0f
#define H 0.02f
#define KHW 12                /* taps +-12h = +-0.24 ~ 4.9 sigma_g */
#define TAPS 25
#define FXS 524288.0f         /* 2^19 fixed-point: worst-case cell <= 2^31 */
#define LOG2E 1.4426950408889634f
#define INV_TWO_PI 0.15915494309189535f

typedef unsigned int u32;

static __device__ __forceinline__ float fast_exp2(float x) {
#if __has_builtin(__builtin_amdgcn_exp2f)
    return __builtin_amdgcn_exp2f(x);
#else
    return exp2f(x);
#endif
}

// Single-kernel grid FGT, one block per batch, everything in LDS.
// Kernel shape: Lambda * G_{sg_g} * Lambda with sg_g^2 = sg^2 - h^2/3
// (variance-compensated). Mass of composite = 2*pi*sg_g^2, so the exact
// output scale is 1/(2*pi*sg_g^2*FXS)  <-- round-8's missing factor.
__global__ __launch_bounds__(TPB)
void kde_fgt(const float* __restrict__ w, const float* __restrict__ c,
             const float* __restrict__ sigma, float* __restrict__ out) {
    __shared__ __align__(16) u32   buf0[NG2];   // rho (u32), later sm (float)
    __shared__ __align__(16) float buf1[NG2];   // tmp

    int b = blockIdx.x, t = threadIdx.x;

    float sg   = sigma[0];
    float sg2g = fmaxf(sg * sg - (H * H) * (1.0f / 3.0f), 0.25f * sg * sg);
    float kapl = LOG2E / (2.0f * sg2g);

    // Gaussian taps in registers (25 exp2, cheap)
    float gt[TAPS];
#pragma unroll
    for (int k = 0; k < TAPS; ++k) {
        float kk = (float)(k - KHW) * H;
        gt[k] = fast_exp2(-kk * kk * kapl);
    }

    // ---- phase 0: zero rho ----
    for (int i = t; i < NG2; i += TPB) buf0[i] = 0u;
    __syncthreads();

    // ---- phase 1: bilinear splat, deterministic LDS integer atomics ----
#pragma unroll
    for (int it = 0; it < NPTS / TPB; ++it) {
        int idx = b * NPTS + it * TPB + t;
        float2 cc = ((const float2*)c)[idx];
        float ww = w[idx] * FXS;
        float u = (cc.x + ORGX) * INVH;
        float v = (cc.y + ORGX) * INVH;
        int iu = min(max((int)floorf(u), 13), 62);
        int iv = min(max((int)floorf(v), 13), 62);
        float fu = fminf(fmaxf(u - (float)iu, 0.0f), 1.0f);
        float fv = fminf(fmaxf(v - (float)iv, 0.0f), 1.0f);
        u32* g = &buf0[iv * NG + iu];
        atomicAdd(&g[0],      (u32)(ww * (1.0f - fu) * (1.0f - fv) + 0.5f));
        atomicAdd(&g[1],      (u32)(ww * fu * (1.0f - fv) + 0.5f));
        atomicAdd(&g[NG],     (u32)(ww * (1.0f - fu) * fv + 0.5f));
        atomicAdd(&g[NG + 1], (u32)(ww * fu * fv + 0.5f));
    }
    __syncthreads();

    // ---- phase 2: horizontal conv, rows [1,76], cols [13,64] in 4-strips ---
    if (t < 76 * 13) {
        int r  = 1 + t / 13;
        int s  = t % 13;
        int c0 = 13 + 4 * s;                  // output cols c0..c0+3
        float win[32];
        const u32* rp = &buf0[r * NG + 4 * s];   // aligned window [4s, 4s+31]
#pragma unroll
        for (int q = 0; q < 32; q += 4) {
            uint4 vv = *(const uint4*)&rp[q];    // ds_read_b128 (16B aligned)
            win[q]     = (float)vv.x;
            win[q + 1] = (float)vv.y;
            win[q + 2] = (float)vv.z;
            win[q + 3] = (float)vv.w;
        }
        float o0 = 0.0f, o1 = 0.0f, o2 = 0.0f, o3 = 0.0f;
#pragma unroll
        for (int k = 0; k < TAPS; ++k) {        // output col c0+j reads win[1+j+k]
            o0 = fmaf(gt[k], win[1 + k], o0);
            o1 = fmaf(gt[k], win[2 + k], o1);
            o2 = fmaf(gt[k], win[3 + k], o2);
            o3 = fmaf(gt[k], win[4 + k], o3);
        }
        buf1[r * NG + c0]     = o0;
        buf1[r * NG + c0 + 1] = o1;
        buf1[r * NG + c0 + 2] = o2;
        buf1[r * NG + c0 + 3] = o3;
    }
    __syncthreads();

    // ---- phase 3: vertical conv, rows [13,64] in 4-strips, cols [13,63] ----
    float* smf = (float*)buf0;                  // overwrite rho with sm
    if (t < 13 * 51) {
        int rs = t / 51;
        int cc = 13 + t % 51;
        int r0 = 13 + 4 * rs;                   // output rows r0..r0+3
        float win[28];
#pragma unroll
        for (int q = 0; q < 28; ++q)            // rows r0-12 .. r0+15
            win[q] = buf1[(r0 - 12 + q) * NG + cc];
        float o0 = 0.0f, o1 = 0.0f, o2 = 0.0f, o3 = 0.0f;
#pragma unroll
        for (int k = 0; k < TAPS; ++k) {
            o0 = fmaf(gt[k], win[k],     o0);
            o1 = fmaf(gt[k], win[k + 1], o1);
            o2 = fmaf(gt[k], win[k + 2], o2);
            o3 = fmaf(gt[k], win[k + 3], o3);
        }
        smf[r0 * NG + cc]       = o0;
        smf[(r0 + 1) * NG + cc] = o1;
        smf[(r0 + 2) * NG + cc] = o2;
        smf[(r0 + 3) * NG + cc] = o3;
    }
    __syncthreads();

    // ---- phase 4: bilinear eval ----
    float scale = INV_TWO_PI / sg2g * (1.0f / FXS);
#pragma unroll
    for (int it = 0; it < NPTS / TPB; ++it) {
        int idx = b * NPTS + it * TPB + t;
        float2 cc = ((const float2*)c)[idx];
        float u = (cc.x + ORGX) * INVH;
        float v = (cc.y + ORGX) * INVH;
        int iu = min(max((int)floorf(u), 13), 62);
        int iv = min(max((int)floorf(v), 13), 62);
        float fu = fminf(fmaxf(u - (float)iu, 0.0f), 1.0f);
        float fv = fminf(fmaxf(v - (float)iv, 0.0f), 1.0f);
        const float* g = &smf[iv * NG + iu];
        float s00 = g[0], s10 = g[1], s01 = g[NG], s11 = g[NG + 1];
        float s0 = s00 + fu * (s10 - s00);
        float s1 = s01 + fu * (s11 - s01);
        out[idx] = (s0 + fv * (s1 - s0)) * scale;
    }
}

extern "C" void kernel_launch(void* const* d_in, const int* in_sizes, int n_in,
                              void* d_out, int out_size, void* d_ws, size_t ws_size,
                              hipStream_t stream) {
    const float* w     = (const float*)d_in[0];
    const float* c     = (const float*)d_in[1];
    const float* sigma = (const float*)d_in[2];
    float* out = (float*)d_out;

    kde_fgt<<<BATCH, TPB, 0, stream>>>(w, c, sigma, out);
}

// Round 10
// 10.945 us; speedup vs baseline: 4.4386x; 1.1335x over previous
//
#include <hip/hip_runtime.h>
#include <math.h>

#define BATCH 8
#define NPTS 4096
#define TPB 1024
#define NG 80
#define NG2 (NG * NG)
#define ORGX 0.26f            /* grid origin -0.26; u=(x+0.26)*50 in [13,63) */
#define INVH 50.0f
#define H 0.02f
#define KHW 10                /* taps +-10h = +-0.2 ~ 4.1 sigma_g */
#define TAPS 21
#define FXS 524288.0f         /* 2^19 fixed-point: sum(w)*FXS < 2^31 */
#define LOG2E 1.4426950408889634f
#define INV_TWO_PI 0.15915494309189535f

typedef unsigned int u32;

static __device__ __forceinline__ float fast_exp2(float x) {
#if __has_builtin(__builtin_amdgcn_exp2f)
    return __builtin_amdgcn_exp2f(x);
#else
    return exp2f(x);
#endif
}

// Single-kernel grid FGT, one block per batch, everything in LDS.
// Composite kernel Lambda*G_{sg_g}*Lambda, sg_g^2 = sg^2 - h^2/3 (variance-
// compensated); output scale 1/(2*pi*sg_g^2*FXS) folded into phase-3 taps.
__global__ __launch_bounds__(TPB)
void kde_fgt(const float* __restrict__ w, const float* __restrict__ c,
             const float* __restrict__ sigma, float* __restrict__ out) {
    __shared__ __align__(16) u32   buf0[NG2];   // rho (u32), later sm (float)
    __shared__ __align__(16) float buf1[NG2];   // tmp

    int b = blockIdx.x, t = threadIdx.x;

    float sg   = sigma[0];
    float sg2g = fmaxf(sg * sg - (H * H) * (1.0f / 3.0f), 0.25f * sg * sg);
    float kapl = LOG2E / (2.0f * sg2g);

    float gt[TAPS];
#pragma unroll
    for (int k = 0; k < TAPS; ++k) {
        float kk = (float)(k - KHW) * H;
        gt[k] = fast_exp2(-kk * kk * kapl);
    }

    // ---- phase 0: zero both buffers ----
    for (int i = t; i < NG2; i += TPB) { buf0[i] = 0u; buf1[i] = 0.0f; }
    __syncthreads();

    // ---- phase 1: bilinear splat (deterministic integer LDS atomics);
    //      cache interp state in registers for phase 4 ----
    int lin_[4]; float fu_[4], fv_[4];
#pragma unroll
    for (int it = 0; it < NPTS / TPB; ++it) {
        int idx = b * NPTS + it * TPB + t;
        float2 cc = ((const float2*)c)[idx];
        float ww = w[idx] * FXS;
        float u = (cc.x + ORGX) * INVH;
        float v = (cc.y + ORGX) * INVH;
        int iu = min(max((int)floorf(u), 13), 62);
        int iv = min(max((int)floorf(v), 13), 62);
        float fu = u - (float)iu;
        float fv = v - (float)iv;
        int lin = iv * NG + iu;
        lin_[it] = lin; fu_[it] = fu; fv_[it] = fv;
        float wb = ww * fu, wa = ww - wb;
        float w01 = wa * fv, w00 = wa - w01;
        float w11 = wb * fv, w10 = wb - w11;
        atomicAdd(&buf0[lin],          (u32)(w00 + 0.5f));
        atomicAdd(&buf0[lin + 1],      (u32)(w10 + 0.5f));
        atomicAdd(&buf0[lin + NG],     (u32)(w01 + 0.5f));
        atomicAdd(&buf0[lin + NG + 1], (u32)(w11 + 0.5f));
    }
    __syncthreads();

    // ---- phase 2: horizontal conv, rows [13,63], 8-col strips ----
    // rho nonzero only rows/cols [13,63] -> 51 rows suffice; buf1 elsewhere
    // stays zero from phase 0.
    if (t < 51 * 7) {
        int r  = 13 + t / 7;
        int s  = t % 7;
        int c0 = 12 + 8 * s;                    // output cols c0..c0+7 (12..67)
        const u32* rp = &buf0[r * NG + 8 * s];  // aligned window cols [8s,8s+31]
        float win[32];
#pragma unroll
        for (int q = 0; q < 32; q += 4) {
            uint4 vv = *(const uint4*)&rp[q];   // ds_read_b128
            win[q]     = (float)vv.x;
            win[q + 1] = (float)vv.y;
            win[q + 2] = (float)vv.z;
            win[q + 3] = (float)vv.w;
        }
        float o[8] = {0, 0, 0, 0, 0, 0, 0, 0};
#pragma unroll
        for (int k = 0; k < TAPS; ++k) {
#pragma unroll
            for (int j = 0; j < 8; ++j)         // col c0+j reads win[2+j+k]
                o[j] = fmaf(gt[k], win[2 + j + k], o[j]);
        }
        *(float4*)&buf1[r * NG + c0]     = make_float4(o[0], o[1], o[2], o[3]);
        *(float4*)&buf1[r * NG + c0 + 4] = make_float4(o[4], o[5], o[6], o[7]);
    }
    __syncthreads();

    // fold final scale into vertical taps (register op, all threads)
    float scale = INV_TWO_PI / sg2g * (1.0f / FXS);
#pragma unroll
    for (int k = 0; k < TAPS; ++k) gt[k] *= scale;

    // ---- phase 3: vertical conv, 8-row strips, cols [13,63] ----
    float* smf = (float*)buf0;                  // overwrite rho with sm
    if (t < 7 * 51) {
        int rs = t / 51;
        int cc = 13 + t % 51;
        int r0 = 13 + 8 * rs;                   // output rows r0..r0+7 (13..68)
        float win[28];
#pragma unroll
        for (int q = 0; q < 28; ++q)            // input rows r0-10 .. r0+17
            win[q] = buf1[(r0 - 10 + q) * NG + cc];
        float o[8] = {0, 0, 0, 0, 0, 0, 0, 0};
#pragma unroll
        for (int k = 0; k < TAPS; ++k) {
#pragma unroll
            for (int j = 0; j < 8; ++j)
                o[j] = fmaf(gt[k], win[j + k], o[j]);
        }
#pragma unroll
        for (int j = 0; j < 8; ++j)
            smf[(r0 + j) * NG + cc] = o[j];
    }
    __syncthreads();

    // ---- phase 4: bilinear eval from cached registers ----
#pragma unroll
    for (int it = 0; it < NPTS / TPB; ++it) {
        int lin = lin_[it];
        float fu = fu_[it], fv = fv_[it];
        float s00 = smf[lin], s10 = smf[lin + 1];
        float s01 = smf[lin + NG], s11 = smf[lin + NG + 1];
        float s0 = s00 + fu * (s10 - s00);
        float s1 = s01 + fu * (s11 - s01);
        out[b * NPTS + it * TPB + t] = s0 + fv * (s1 - s0);
    }
}

extern "C" void kernel_launch(void* const* d_in, const int* in_sizes, int n_in,
                              void* d_out, int out_size, void* d_ws, size_t ws_size,
                              hipStream_t stream) {
    const float* w     = (const float*)d_in[0];
    const float* c     = (const float*)d_in[1];
    const float* sigma = (const float*)d_in[2];
    float* out = (float*)d_out;

    kde_fgt<<<BATCH, TPB, 0, stream>>>(w, c, sigma, out);
}